// Round 13
// baseline (266.612 us; speedup 1.0000x reference)
//
#include <hip/hip_runtime.h>
#include <hip/hip_fp16.h>

#define NN 100000
#define NE 1600000
#define NEG_SLOPE 0.01f

#define NTL(x) __builtin_nontemporal_load(&(x))
typedef float fvec4 __attribute__((ext_vector_type(4)));
typedef float fvec2 __attribute__((ext_vector_type(2)));

// Coarse buckets: 256 consecutive dst nodes each.
#define NB     391        // ceil(NN/256)
#define TILE   4096       // edges per binning workgroup
#define NTILES 391        // ceil(NE/TILE)
#define CAP    8192       // LDS stage capacity per bucket

#define G1_BLOCKS 512
#define G1_WAVES  (G1_BLOCKS * 4)

// ---------------------------------------------------------------------------
// Workspace layout (bytes) — total 26,008,384 B (< 26.4 MB proven).
//   offs  : (NN+1) int  @ 0          (400,004)
//   bcnt  : NB int      @ 400,384
//   boffs : (NB+1) int  @ 402,432
//   gcur  : NB int      @ 404,432
//   csrp  : NE int      @ 408,384    packed (src<<15 | w*32767), by dst, 6.4 MB
//   binned: NE int2     @ 6,808,384  bucket-grouped, 12.8 MB
//   Yq    : NN*64 fp8   @ 6,808,384  (ALIASES binned; binned dead before gemm1)
//   hw    : NN*32 fp16  @ 19,608,384 (6.4 MB)
#define OFF_BCNT  400384
#define OFF_BOFFS 402432
#define OFF_GCUR  404432
#define OFF_CSR   408384
#define OFF_YQ    6808384
#define OFF_HW    19608384

// ---------------------------------------------------------------------------
// A1: per-bucket edge counts (proven round 10).
__global__ __launch_bounds__(256) void k_bucketcnt(const int* __restrict__ dst,
                                                   int* __restrict__ bcnt)
{
    __shared__ int h[NB];
    int t = threadIdx.x;
    for (int i = t; i < NB; i += 256) h[i] = 0;
    __syncthreads();
    int base = blockIdx.x * TILE;
    for (int i = t; i < TILE; i += 256) {
        int e = base + i;
        if (e < NE) atomicAdd(&h[NTL(dst[e]) >> 8], 1);
    }
    __syncthreads();
    for (int i = t; i < NB; i += 256)
        if (h[i]) atomicAdd(&bcnt[i], h[i]);
}

// A2: exclusive scan of bucket counts (proven round 10).
__global__ __launch_bounds__(512) void k_bucketscan(const int* __restrict__ bcnt,
                                                    int* __restrict__ boffs,
                                                    int* __restrict__ gcur)
{
    __shared__ int lds[512];
    int t = threadIdx.x;
    int v = (t < NB) ? bcnt[t] : 0;
    lds[t] = v;
    __syncthreads();
    for (int off = 1; off < 512; off <<= 1) {
        int x = (t >= off) ? lds[t - off] : 0;
        __syncthreads();
        lds[t] += x;
        __syncthreads();
    }
    int excl = lds[t] - v;
    if (t < NB) { boffs[t] = excl; gcur[t] = excl; }
    if (t == NB - 1) boffs[NB] = lds[t];           // == NE
}

// A3: bin edges into bucket-grouped 'binned' (proven round 10).
__global__ __launch_bounds__(256) void k_binscatter(const int* __restrict__ dst,
                                                    const int* __restrict__ esrc,
                                                    const float* __restrict__ ew,
                                                    int* __restrict__ gcur,
                                                    int2* __restrict__ binned)
{
    __shared__ int   hist[NB];
    __shared__ int   cstart[NB];
    __shared__ int   ccur[NB];
    __shared__ int   gb[NB];
    __shared__ int   lds2[256];
    __shared__ int   sdst[TILE];
    __shared__ short sbuck[TILE];
    __shared__ int2  stage[TILE];

    int t = threadIdx.x;
    int base = blockIdx.x * TILE;
    int nvalid = NE - base; if (nvalid > TILE) nvalid = TILE;

    for (int i = t; i < NB; i += 256) hist[i] = 0;
    __syncthreads();
    for (int i = t; i < TILE; i += 256) {
        int e = base + i;
        int d = (e < NE) ? NTL(dst[e]) : -1;
        sdst[i] = d;
        if (d >= 0) atomicAdd(&hist[d >> 8], 1);
    }
    __syncthreads();

    int h0 = (2 * t     < NB) ? hist[2 * t]     : 0;
    int h1 = (2 * t + 1 < NB) ? hist[2 * t + 1] : 0;
    int ps = h0 + h1;
    lds2[t] = ps;
    __syncthreads();
    for (int off = 1; off < 256; off <<= 1) {
        int x = (t >= off) ? lds2[t - off] : 0;
        __syncthreads();
        lds2[t] += x;
        __syncthreads();
    }
    int excl = lds2[t] - ps;
    if (2 * t     < NB) { cstart[2 * t]     = excl;      ccur[2 * t]     = excl; }
    if (2 * t + 1 < NB) { cstart[2 * t + 1] = excl + h0; ccur[2 * t + 1] = excl + h0; }
    __syncthreads();

    for (int i = t; i < TILE; i += 256) {
        int d = sdst[i];
        if (d >= 0) {
            int e = base + i;
            int b = d >> 8;
            int pos = atomicAdd(&ccur[b], 1);
            stage[pos] = make_int2((NTL(esrc[e]) << 8) | (d & 255),
                                   __float_as_int(NTL(ew[e])));
            sbuck[pos] = (short)b;
        }
    }
    __syncthreads();

    for (int i = t; i < NB; i += 256)
        if (hist[i]) gb[i] = atomicAdd(&gcur[i], hist[i]);
    __syncthreads();
    for (int i = t; i < nvalid; i += 256) {
        int b = sbuck[i];
        binned[gb[b] + (i - cstart[b])] = stage[i];
    }
}

// B: per-bucket LDS counting sort -> csrp + offs (proven round 10).
__global__ __launch_bounds__(256) void k_bucketsort(const int2* __restrict__ binned,
                                                    const int* __restrict__ boffs,
                                                    int* __restrict__ offs,
                                                    int* __restrict__ csrp)
{
    __shared__ int nhist[256];
    __shared__ int nstart[256];
    __shared__ int ncur[256];
    __shared__ int lds[256];
    __shared__ int stage[CAP];

    int t = threadIdx.x, b = blockIdx.x;           // grid = NB
    int s0 = boffs[b], s1 = boffs[b + 1];
    int cnt = s1 - s0;

    nhist[t] = 0;
    __syncthreads();
    for (int i = t; i < cnt; i += 256)
        atomicAdd(&nhist[binned[s0 + i].x & 255], 1);
    __syncthreads();

    int v = nhist[t];
    lds[t] = v;
    __syncthreads();
    for (int off = 1; off < 256; off <<= 1) {
        int x = (t >= off) ? lds[t - off] : 0;
        __syncthreads();
        lds[t] += x;
        __syncthreads();
    }
    int excl = lds[t] - v;
    nstart[t] = excl;
    ncur[t] = excl;
    int node = b * 256 + t;
    if (node < NN) offs[node] = s0 + excl;
    if (b == NB - 1 && t == 0) offs[NN] = s1;      // == NE
    __syncthreads();

    for (int i = t; i < cnt; i += 256) {
        int2 r = binned[s0 + i];
        int dl = r.x & 255;
        unsigned src = ((unsigned)r.x) >> 8;
        float w = __int_as_float(r.y);
        unsigned wq = (unsigned)(w * 32767.0f + 0.5f);
        int pos = atomicAdd(&ncur[dl], 1);
        stage[pos] = (int)((src << 15) | wq);
    }
    __syncthreads();
    for (int i = t; i < cnt; i += 256)
        csrp[s0 + i] = stage[i];
}

// ---------------------------------------------------------------------------
// Y = feats @ W1 -> fp8 e4m3 (HW packed cvt). W1-in-registers (proven r11);
// new epilogue packs 4 lanes' columns into one int and stores 16 ints/row.
__global__ __launch_bounds__(256) void k_gemm1(const float* __restrict__ feats,
                                               const float* __restrict__ W1,
                                               unsigned char* __restrict__ Yq)
{
    int lane = threadIdx.x & 63;
    int wid = (blockIdx.x * 256 + threadIdx.x) >> 6;

    float w[64];
    #pragma unroll
    for (int k = 0; k < 64; ++k) w[k] = W1[k * 64 + lane];

    for (int r = wid; r < NN; r += G1_WAVES) {
        const float4* fr = (const float4*)(feats + r * 64);
        float acc = 0.f;
        #pragma unroll
        for (int i = 0; i < 16; ++i) {
            float4 v = fr[i];
            acc = fmaf(v.x, w[4 * i + 0], acc);
            acc = fmaf(v.y, w[4 * i + 1], acc);
            acc = fmaf(v.z, w[4 * i + 2], acc);
            acc = fmaf(v.w, w[4 * i + 3], acc);
        }
        // pack cols 4j..4j+3 into an int on lane 4j (byte0 = col 4j)
        float accN = __shfl_xor(acc, 1, 64);            // neighbor column
        int v01 = __builtin_amdgcn_cvt_pk_fp8_f32(acc, accN, 0, false);
        int v23 = __shfl_xor(v01, 2, 64);               // cols +2,+3 pair
        int word = (v01 & 0xFFFF) | (v23 << 16);
        if ((lane & 3) == 0)
            ((int*)(Yq + r * 64))[lane >> 2] = word;    // 16 ints = 64 B row
    }
}

// decode+fma 8 fp8 lanes of an 8B packet into 8 f32 accumulators.
__device__ __forceinline__ void fma8q(const int2& raw, float w,
    float& a0, float& a1, float& a2, float& a3,
    float& a4, float& a5, float& a6, float& a7)
{
    fvec2 f;
    f = __builtin_amdgcn_cvt_pk_f32_fp8(raw.x, false);
    a0 = fmaf(w, f.x, a0); a1 = fmaf(w, f.y, a1);
    f = __builtin_amdgcn_cvt_pk_f32_fp8(raw.x, true);
    a2 = fmaf(w, f.x, a2); a3 = fmaf(w, f.y, a3);
    f = __builtin_amdgcn_cvt_pk_f32_fp8(raw.y, false);
    a4 = fmaf(w, f.x, a4); a5 = fmaf(w, f.y, a5);
    f = __builtin_amdgcn_cvt_pk_f32_fp8(raw.y, true);
    a6 = fmaf(w, f.x, a6); a7 = fmaf(w, f.y, a7);
}

// fma 8 fp16 lanes of a 16B packet into 8 f32 accumulators (l2 path).
__device__ __forceinline__ void fma8(const int4& raw, float w,
    float& a0, float& a1, float& a2, float& a3,
    float& a4, float& a5, float& a6, float& a7)
{
    const __half2* hp = (const __half2*)&raw;
    float2 f;
    f = __half22float2(hp[0]); a0 = fmaf(w, f.x, a0); a1 = fmaf(w, f.y, a1);
    f = __half22float2(hp[1]); a2 = fmaf(w, f.x, a2); a3 = fmaf(w, f.y, a3);
    f = __half22float2(hp[2]); a4 = fmaf(w, f.x, a4); a5 = fmaf(w, f.y, a5);
    f = __half22float2(hp[3]); a6 = fmaf(w, f.x, a6); a7 = fmaf(w, f.y, a7);
}

#define RED8(MASK) \
    a0 += __shfl_xor(a0, MASK, 64); a1 += __shfl_xor(a1, MASK, 64); \
    a2 += __shfl_xor(a2, MASK, 64); a3 += __shfl_xor(a3, MASK, 64); \
    a4 += __shfl_xor(a4, MASK, 64); a5 += __shfl_xor(a5, MASK, 64); \
    a6 += __shfl_xor(a6, MASK, 64); a7 += __shfl_xor(a7, MASK, 64);

#define WDEC(c) ((float)((c) & 0x7fffu) * (1.0f / 32767.0f))

// ---------------------------------------------------------------------------
// Layer 1: aggY[n] = sum w*Yq[src] (fp8 gather: 8 edge-slots x 8 lanes x 8B,
// table 6.4 MB -> ~62% L2 hit); h = lrelu(aggY+b1); hw[n] = h@W2 (fp16).
__global__ __launch_bounds__(256) void k_l1(const int* __restrict__ offs,
                                            const int* __restrict__ csrp,
                                            const unsigned char* __restrict__ Yq,
                                            const float* __restrict__ b1,
                                            const float* __restrict__ W2,
                                            __half* __restrict__ hw)
{
    __shared__ float sW2[64][32];
    int tid = threadIdx.x;
    for (int i = tid; i < 64 * 32; i += 256) sW2[i >> 5][i & 31] = W2[i];
    __syncthreads();

    int lane = tid & 63;
    int n = blockIdx.x * 4 + (tid >> 6);           // grid exact = NN waves
    int start = offs[n], end = offs[n + 1];

    int sub = lane >> 3;          // edge slot 0..7
    int e8  = lane & 7;           // octet: Y cols [8*e8, 8*e8+8)

    float a0=0,a1=0,a2=0,a3=0,a4=0,a5=0,a6=0,a7=0;
    for (int base = start; base < end; base += 64) {
        int m = end - base; if (m > 64) m = 64;
        int ed = (lane < m) ? NTL(csrp[base + lane]) : 0;   // pad: s=0, w=0
        int iters = (m + 7) >> 3;
        for (int i = 0; i < iters; ++i) {
            unsigned c = (unsigned)__shfl(ed, (i << 3) + sub, 64);
            const int2 raw = *(const int2*)(Yq + (c >> 15) * 64 + (e8 << 3));
            fma8q(raw, WDEC(c), a0,a1,a2,a3,a4,a5,a6,a7);
        }
    }
    RED8(8) RED8(16) RED8(32)

    const float4 bA = *(const float4*)(b1 + (e8 << 3));
    const float4 bB = *(const float4*)(b1 + (e8 << 3) + 4);
    float h0=a0+bA.x, h1=a1+bA.y, h2=a2+bA.z, h3=a3+bA.w;
    float h4=a4+bB.x, h5=a5+bB.y, h6=a6+bB.z, h7=a7+bB.w;
    h0 = h0>=0.f ? h0 : NEG_SLOPE*h0;  h1 = h1>=0.f ? h1 : NEG_SLOPE*h1;
    h2 = h2>=0.f ? h2 : NEG_SLOPE*h2;  h3 = h3>=0.f ? h3 : NEG_SLOPE*h3;
    h4 = h4>=0.f ? h4 : NEG_SLOPE*h4;  h5 = h5>=0.f ? h5 : NEG_SLOPE*h5;
    h6 = h6>=0.f ? h6 : NEG_SLOPE*h6;  h7 = h7>=0.f ? h7 : NEG_SLOPE*h7;

    int half = lane >> 5, c = lane & 31;
    int sbase = half << 2;
    float p = 0.f;
    #pragma unroll
    for (int kk = 0; kk < 32; ++kk) {
        float comp = (kk&7)==0 ? h0 : (kk&7)==1 ? h1 : (kk&7)==2 ? h2
                   : (kk&7)==3 ? h3 : (kk&7)==4 ? h4 : (kk&7)==5 ? h5
                   : (kk&7)==6 ? h6 : h7;              // static after unroll
        float hk = __shfl(comp, sbase + (kk >> 3), 64);
        p = fmaf(hk, sW2[(half << 5) + kk][c], p);
    }
    p += __shfl_xor(p, 32, 64);
    if (lane < 32) hw[n * 32 + lane] = __float2half(p);
}

// ---------------------------------------------------------------------------
// Layer 2: out[n] = b2 + sum w*hw[src]. Two nodes per wave (proven r12).
__global__ __launch_bounds__(256) void k_l2(const int* __restrict__ offs,
                                            const int* __restrict__ csrp,
                                            const __half* __restrict__ hw,
                                            const float* __restrict__ b2,
                                            float* __restrict__ out)
{
    int tid = threadIdx.x;
    int lane = tid & 63;
    int wid = blockIdx.x * 4 + (tid >> 6);         // grid exact = NN/2 waves
    int nA = wid * 2, nB = nA + 1;
    int sA = offs[nA], eA = offs[nA + 1];
    int sB = offs[nB], eB = offs[nB + 1];

    int sub = lane >> 2;          // edge slot 0..15
    int e8  = lane & 3;           // octet: cols [8*e8, 8*e8+8)

    float a0=0,a1=0,a2=0,a3=0,a4=0,a5=0,a6=0,a7=0;          // node A
    float g0=0,g1=0,g2=0,g3=0,g4=0,g5=0,g6=0,g7=0;          // node B
    for (int bA = sA, bB = sB; bA < eA || bB < eB; bA += 64, bB += 64) {
        int mA = eA - bA; mA = mA < 0 ? 0 : (mA > 64 ? 64 : mA);
        int mB = eB - bB; mB = mB < 0 ? 0 : (mB > 64 ? 64 : mB);
        int edA = (lane < mA) ? NTL(csrp[bA + lane]) : 0;   // pad: s=0, w=0
        int edB = (lane < mB) ? NTL(csrp[bB + lane]) : 0;
        int itA = (mA + 15) >> 4, itB = (mB + 15) >> 4;
        int it = itA > itB ? itA : itB;
        for (int i = 0; i < it; ++i) {
            unsigned cA = (unsigned)__shfl(edA, (i << 4) + sub, 64);
            unsigned cB = (unsigned)__shfl(edB, (i << 4) + sub, 64);
            const int4 rA = *(const int4*)(hw + (cA >> 15) * 32 + (e8 << 3));
            const int4 rB = *(const int4*)(hw + (cB >> 15) * 32 + (e8 << 3));
            fma8(rA, WDEC(cA), a0,a1,a2,a3,a4,a5,a6,a7);
            fma8(rB, WDEC(cB), g0,g1,g2,g3,g4,g5,g6,g7);
        }
    }
    RED8(4) RED8(8) RED8(16) RED8(32)
    #define REDG(MASK) \
        g0 += __shfl_xor(g0, MASK, 64); g1 += __shfl_xor(g1, MASK, 64); \
        g2 += __shfl_xor(g2, MASK, 64); g3 += __shfl_xor(g3, MASK, 64); \
        g4 += __shfl_xor(g4, MASK, 64); g5 += __shfl_xor(g5, MASK, 64); \
        g6 += __shfl_xor(g6, MASK, 64); g7 += __shfl_xor(g7, MASK, 64);
    REDG(4) REDG(8) REDG(16) REDG(32)

    if (lane < 4) {
        int cb = lane << 3;
        fvec4 o0 = { a0 + b2[cb+0], a1 + b2[cb+1], a2 + b2[cb+2], a3 + b2[cb+3] };
        fvec4 o1 = { a4 + b2[cb+4], a5 + b2[cb+5], a6 + b2[cb+6], a7 + b2[cb+7] };
        fvec4 o2 = { g0 + b2[cb+0], g1 + b2[cb+1], g2 + b2[cb+2], g3 + b2[cb+3] };
        fvec4 o3 = { g4 + b2[cb+4], g5 + b2[cb+5], g6 + b2[cb+6], g7 + b2[cb+7] };
        __builtin_nontemporal_store(o0, (fvec4*)(out + nA * 32 + cb));
        __builtin_nontemporal_store(o1, (fvec4*)(out + nA * 32 + cb + 4));
        __builtin_nontemporal_store(o2, (fvec4*)(out + nB * 32 + cb));
        __builtin_nontemporal_store(o3, (fvec4*)(out + nB * 32 + cb + 4));
    }
}

// ---------------------------------------------------------------------------
extern "C" void kernel_launch(void* const* d_in, const int* in_sizes, int n_in,
                              void* d_out, int out_size, void* d_ws, size_t ws_size,
                              hipStream_t stream)
{
    const float* feats = (const float*)d_in[0];
    const int*   esrc  = (const int*)d_in[1];
    const int*   edst  = (const int*)d_in[2];
    const float* ew    = (const float*)d_in[3];
    const float* W1    = (const float*)d_in[4];
    const float* b1    = (const float*)d_in[5];
    const float* W2    = (const float*)d_in[6];
    const float* b2    = (const float*)d_in[7];
    float* out = (float*)d_out;

    char*          ws     = (char*)d_ws;
    int*           offs   = (int*)ws;
    int*           bcnt   = (int*)(ws + OFF_BCNT);
    int*           boffs  = (int*)(ws + OFF_BOFFS);
    int*           gcur   = (int*)(ws + OFF_GCUR);
    int*           csrp   = (int*)(ws + OFF_CSR);
    int2*          binned = (int2*)(ws + OFF_YQ);  // aliases Yq; dead before gemm1
    unsigned char* Yq     = (unsigned char*)(ws + OFF_YQ);
    __half*        hw     = (__half*)(ws + OFF_HW);

    (void)hipMemsetAsync(bcnt, 0, NB * sizeof(int), stream);

    k_bucketcnt <<<NTILES,    256, 0, stream>>>(edst, bcnt);
    k_bucketscan<<<1,         512, 0, stream>>>(bcnt, boffs, gcur);
    k_binscatter<<<NTILES,    256, 0, stream>>>(edst, esrc, ew, gcur, binned);
    k_bucketsort<<<NB,        256, 0, stream>>>(binned, boffs, offs, csrp);
    k_gemm1     <<<G1_BLOCKS, 256, 0, stream>>>(feats, W1, Yq);
    k_l1        <<<NN / 4,    256, 0, stream>>>(offs, csrp, Yq, b1, W2, hw);
    k_l2        <<<NN / 8,    256, 0, stream>>>(offs, csrp, hw, b2, out);
}

// Round 14
// 231.003 us; speedup vs baseline: 1.1542x; 1.1542x over previous
//
#include <hip/hip_runtime.h>
#include <hip/hip_fp16.h>

#define NN 100000
#define NE 1600000
#define NEG_SLOPE 0.01f

#define NTL(x) __builtin_nontemporal_load(&(x))
typedef float fvec4 __attribute__((ext_vector_type(4)));
typedef float fvec2 __attribute__((ext_vector_type(2)));

// Coarse buckets: 256 consecutive dst nodes each.
#define NB     391        // ceil(NN/256)
#define TILE   4096       // edges per binning workgroup
#define NTILES 391        // ceil(NE/TILE)
#define CAP    8192       // LDS stage capacity per bucket

#define G1_BLOCKS 512
#define G1_WAVES  (G1_BLOCKS * 4)

// ---------------------------------------------------------------------------
// Workspace layout (bytes) — total 26,008,384 B (< 26.4 MB proven).
//   offs  : (NN+1) int  @ 0          (400,004)
//   bcnt  : NB int      @ 400,384
//   boffs : (NB+1) int  @ 402,432
//   gcur  : NB int      @ 404,432
//   csrp  : NE int      @ 408,384    packed (src<<15 | w*32767), by dst, 6.4 MB
//   binned: NE int2     @ 6,808,384  bucket-grouped, 12.8 MB
//   Yq    : NN*64 fp8   @ 6,808,384  (ALIASES binned; binned dead before gemm1)
//   hw    : NN*32 fp16  @ 19,608,384 (6.4 MB)
#define OFF_BCNT  400384
#define OFF_BOFFS 402432
#define OFF_GCUR  404432
#define OFF_CSR   408384
#define OFF_YQ    6808384
#define OFF_HW    19608384

// ---------------------------------------------------------------------------
// A1: per-bucket edge counts (proven round 10).
__global__ __launch_bounds__(256) void k_bucketcnt(const int* __restrict__ dst,
                                                   int* __restrict__ bcnt)
{
    __shared__ int h[NB];
    int t = threadIdx.x;
    for (int i = t; i < NB; i += 256) h[i] = 0;
    __syncthreads();
    int base = blockIdx.x * TILE;
    for (int i = t; i < TILE; i += 256) {
        int e = base + i;
        if (e < NE) atomicAdd(&h[NTL(dst[e]) >> 8], 1);
    }
    __syncthreads();
    for (int i = t; i < NB; i += 256)
        if (h[i]) atomicAdd(&bcnt[i], h[i]);
}

// A2: exclusive scan of bucket counts (proven round 10).
__global__ __launch_bounds__(512) void k_bucketscan(const int* __restrict__ bcnt,
                                                    int* __restrict__ boffs,
                                                    int* __restrict__ gcur)
{
    __shared__ int lds[512];
    int t = threadIdx.x;
    int v = (t < NB) ? bcnt[t] : 0;
    lds[t] = v;
    __syncthreads();
    for (int off = 1; off < 512; off <<= 1) {
        int x = (t >= off) ? lds[t - off] : 0;
        __syncthreads();
        lds[t] += x;
        __syncthreads();
    }
    int excl = lds[t] - v;
    if (t < NB) { boffs[t] = excl; gcur[t] = excl; }
    if (t == NB - 1) boffs[NB] = lds[t];           // == NE
}

// A3: bin edges into bucket-grouped 'binned' (proven round 10).
__global__ __launch_bounds__(256) void k_binscatter(const int* __restrict__ dst,
                                                    const int* __restrict__ esrc,
                                                    const float* __restrict__ ew,
                                                    int* __restrict__ gcur,
                                                    int2* __restrict__ binned)
{
    __shared__ int   hist[NB];
    __shared__ int   cstart[NB];
    __shared__ int   ccur[NB];
    __shared__ int   gb[NB];
    __shared__ int   lds2[256];
    __shared__ int   sdst[TILE];
    __shared__ short sbuck[TILE];
    __shared__ int2  stage[TILE];

    int t = threadIdx.x;
    int base = blockIdx.x * TILE;
    int nvalid = NE - base; if (nvalid > TILE) nvalid = TILE;

    for (int i = t; i < NB; i += 256) hist[i] = 0;
    __syncthreads();
    for (int i = t; i < TILE; i += 256) {
        int e = base + i;
        int d = (e < NE) ? NTL(dst[e]) : -1;
        sdst[i] = d;
        if (d >= 0) atomicAdd(&hist[d >> 8], 1);
    }
    __syncthreads();

    int h0 = (2 * t     < NB) ? hist[2 * t]     : 0;
    int h1 = (2 * t + 1 < NB) ? hist[2 * t + 1] : 0;
    int ps = h0 + h1;
    lds2[t] = ps;
    __syncthreads();
    for (int off = 1; off < 256; off <<= 1) {
        int x = (t >= off) ? lds2[t - off] : 0;
        __syncthreads();
        lds2[t] += x;
        __syncthreads();
    }
    int excl = lds2[t] - ps;
    if (2 * t     < NB) { cstart[2 * t]     = excl;      ccur[2 * t]     = excl; }
    if (2 * t + 1 < NB) { cstart[2 * t + 1] = excl + h0; ccur[2 * t + 1] = excl + h0; }
    __syncthreads();

    for (int i = t; i < TILE; i += 256) {
        int d = sdst[i];
        if (d >= 0) {
            int e = base + i;
            int b = d >> 8;
            int pos = atomicAdd(&ccur[b], 1);
            stage[pos] = make_int2((NTL(esrc[e]) << 8) | (d & 255),
                                   __float_as_int(NTL(ew[e])));
            sbuck[pos] = (short)b;
        }
    }
    __syncthreads();

    for (int i = t; i < NB; i += 256)
        if (hist[i]) gb[i] = atomicAdd(&gcur[i], hist[i]);
    __syncthreads();
    for (int i = t; i < nvalid; i += 256) {
        int b = sbuck[i];
        binned[gb[b] + (i - cstart[b])] = stage[i];
    }
}

// B: per-bucket LDS counting sort -> csrp + offs (proven round 10).
__global__ __launch_bounds__(256) void k_bucketsort(const int2* __restrict__ binned,
                                                    const int* __restrict__ boffs,
                                                    int* __restrict__ offs,
                                                    int* __restrict__ csrp)
{
    __shared__ int nhist[256];
    __shared__ int nstart[256];
    __shared__ int ncur[256];
    __shared__ int lds[256];
    __shared__ int stage[CAP];

    int t = threadIdx.x, b = blockIdx.x;           // grid = NB
    int s0 = boffs[b], s1 = boffs[b + 1];
    int cnt = s1 - s0;

    nhist[t] = 0;
    __syncthreads();
    for (int i = t; i < cnt; i += 256)
        atomicAdd(&nhist[binned[s0 + i].x & 255], 1);
    __syncthreads();

    int v = nhist[t];
    lds[t] = v;
    __syncthreads();
    for (int off = 1; off < 256; off <<= 1) {
        int x = (t >= off) ? lds[t - off] : 0;
        __syncthreads();
        lds[t] += x;
        __syncthreads();
    }
    int excl = lds[t] - v;
    nstart[t] = excl;
    ncur[t] = excl;
    int node = b * 256 + t;
    if (node < NN) offs[node] = s0 + excl;
    if (b == NB - 1 && t == 0) offs[NN] = s1;      // == NE
    __syncthreads();

    for (int i = t; i < cnt; i += 256) {
        int2 r = binned[s0 + i];
        int dl = r.x & 255;
        unsigned src = ((unsigned)r.x) >> 8;
        float w = __int_as_float(r.y);
        unsigned wq = (unsigned)(w * 32767.0f + 0.5f);
        int pos = atomicAdd(&ncur[dl], 1);
        stage[pos] = (int)((src << 15) | wq);
    }
    __syncthreads();
    for (int i = t; i < cnt; i += 256)
        csrp[s0 + i] = stage[i];
}

// ---------------------------------------------------------------------------
// Y = feats @ W1 -> fp8 e4m3 (proven round 13).
__global__ __launch_bounds__(256) void k_gemm1(const float* __restrict__ feats,
                                               const float* __restrict__ W1,
                                               unsigned char* __restrict__ Yq)
{
    int lane = threadIdx.x & 63;
    int wid = (blockIdx.x * 256 + threadIdx.x) >> 6;

    float w[64];
    #pragma unroll
    for (int k = 0; k < 64; ++k) w[k] = W1[k * 64 + lane];

    for (int r = wid; r < NN; r += G1_WAVES) {
        const float4* fr = (const float4*)(feats + r * 64);
        float acc = 0.f;
        #pragma unroll
        for (int i = 0; i < 16; ++i) {
            float4 v = fr[i];
            acc = fmaf(v.x, w[4 * i + 0], acc);
            acc = fmaf(v.y, w[4 * i + 1], acc);
            acc = fmaf(v.z, w[4 * i + 2], acc);
            acc = fmaf(v.w, w[4 * i + 3], acc);
        }
        float accN = __shfl_xor(acc, 1, 64);
        int v01 = __builtin_amdgcn_cvt_pk_fp8_f32(acc, accN, 0, false);
        int v23 = __shfl_xor(v01, 2, 64);
        int word = (v01 & 0xFFFF) | (v23 << 16);
        if ((lane & 3) == 0)
            ((int*)(Yq + r * 64))[lane >> 2] = word;
    }
}

#define WDEC(c) ((float)((c) & 0x7fffu) * (1.0f / 32767.0f))

// ---------------------------------------------------------------------------
// Layer 1 (round 14 rewrite — DS-pipe diet):
//  gather: 4 edge-slots x 16 lanes x 4B fp8 (4 cols/lane, 4 accumulators)
//  RED: 8 shfl (masks 16,32)  [was 24]
//  W2 matmul: W2 column in 32 VGPRs (loaded once); h staged via 1 KB per-wave
//  LDS (1 ds_write_b128 + 8 broadcast ds_read_b128)  [was 32 shfl + 32 LDS]
__global__ __launch_bounds__(256) void k_l1(const int* __restrict__ offs,
                                            const int* __restrict__ csrp,
                                            const unsigned char* __restrict__ Yq,
                                            const float* __restrict__ b1,
                                            const float* __restrict__ W2,
                                            __half* __restrict__ hw)
{
    __shared__ __align__(16) float sh[4][64];      // per-wave h staging
    int tid = threadIdx.x;
    int lane = tid & 63;
    int wv = tid >> 6;
    int n = blockIdx.x * 4 + wv;                   // grid exact = NN waves
    int half = lane >> 5, c = lane & 31;

    // W2[k][c] for k in [half*32, half*32+32) — 32 VGPRs, loaded once.
    float w2r[32];
    #pragma unroll
    for (int kk = 0; kk < 32; ++kk)
        w2r[kk] = W2[(half * 32 + kk) * 32 + c];

    int sub = lane >> 4;          // edge slot 0..3
    int e4  = lane & 15;          // col quad: cols [4*e4, 4*e4+4)
    const float4 bq = *(const float4*)(b1 + (e4 << 2));

    int start = offs[n], end = offs[n + 1];
    float a0 = 0.f, a1 = 0.f, a2 = 0.f, a3 = 0.f;
    for (int base = start; base < end; base += 64) {
        int m = end - base; if (m > 64) m = 64;
        int ed = (lane < m) ? NTL(csrp[base + lane]) : 0;   // pad: s=0, w=0
        int iters = (m + 3) >> 2;
        for (int i = 0; i < iters; ++i) {
            unsigned cc = (unsigned)__shfl(ed, (i << 2) + sub, 64);
            unsigned w8 = *(const unsigned*)(Yq + (cc >> 15) * 64 + (e4 << 2));
            float w = WDEC(cc);
            fvec2 lo = __builtin_amdgcn_cvt_pk_f32_fp8((int)w8, false);
            fvec2 hi = __builtin_amdgcn_cvt_pk_f32_fp8((int)w8, true);
            a0 = fmaf(w, lo.x, a0); a1 = fmaf(w, lo.y, a1);
            a2 = fmaf(w, hi.x, a2); a3 = fmaf(w, hi.y, a3);
        }
    }
    a0 += __shfl_xor(a0, 16, 64); a1 += __shfl_xor(a1, 16, 64);
    a2 += __shfl_xor(a2, 16, 64); a3 += __shfl_xor(a3, 16, 64);
    a0 += __shfl_xor(a0, 32, 64); a1 += __shfl_xor(a1, 32, 64);
    a2 += __shfl_xor(a2, 32, 64); a3 += __shfl_xor(a3, 32, 64);

    float h0 = a0 + bq.x, h1 = a1 + bq.y, h2 = a2 + bq.z, h3 = a3 + bq.w;
    h0 = h0 >= 0.f ? h0 : NEG_SLOPE * h0;  h1 = h1 >= 0.f ? h1 : NEG_SLOPE * h1;
    h2 = h2 >= 0.f ? h2 : NEG_SLOPE * h2;  h3 = h3 >= 0.f ? h3 : NEG_SLOPE * h3;

    if (sub == 0)
        *(float4*)&sh[wv][e4 << 2] = make_float4(h0, h1, h2, h3);
    __builtin_amdgcn_wave_barrier();               // keep write before reads

    float p = 0.f;
    #pragma unroll
    for (int q = 0; q < 8; ++q) {                  // broadcast reads, no conflicts
        float4 hv = *(const float4*)&sh[wv][(half << 5) + (q << 2)];
        p = fmaf(hv.x, w2r[4 * q + 0], p);
        p = fmaf(hv.y, w2r[4 * q + 1], p);
        p = fmaf(hv.z, w2r[4 * q + 2], p);
        p = fmaf(hv.w, w2r[4 * q + 3], p);
    }
    p += __shfl_xor(p, 32, 64);
    if (lane < 32) hw[n * 32 + lane] = __float2half(p);
}

// ---------------------------------------------------------------------------
// Layer 2 (round 14 rewrite): 8 edge-slots x 8 lanes x 8B fp16 (4 cols/lane,
// 4 accumulators). RED = 12 shfl (was 32/node). Direct NT store from sub 0.
__global__ __launch_bounds__(256) void k_l2(const int* __restrict__ offs,
                                            const int* __restrict__ csrp,
                                            const __half* __restrict__ hw,
                                            const float* __restrict__ b2,
                                            float* __restrict__ out)
{
    int tid = threadIdx.x;
    int lane = tid & 63;
    int n = blockIdx.x * 4 + (tid >> 6);           // grid exact = NN waves
    int sub = lane >> 3;          // edge slot 0..7
    int e4  = lane & 7;           // col quad: cols [4*e4, 4*e4+4)
    const float4 bq = *(const float4*)(b2 + (e4 << 2));

    int start = offs[n], end = offs[n + 1];
    float a0 = 0.f, a1 = 0.f, a2 = 0.f, a3 = 0.f;
    for (int base = start; base < end; base += 64) {
        int m = end - base; if (m > 64) m = 64;
        int ed = (lane < m) ? NTL(csrp[base + lane]) : 0;   // pad: s=0, w=0
        int iters = (m + 7) >> 3;
        for (int i = 0; i < iters; ++i) {
            unsigned cc = (unsigned)__shfl(ed, (i << 3) + sub, 64);
            int2 raw = *(const int2*)(hw + (cc >> 15) * 32 + (e4 << 2));
            float w = WDEC(cc);
            float2 f0 = __half22float2(((const __half2*)&raw)[0]);
            float2 f1 = __half22float2(((const __half2*)&raw)[1]);
            a0 = fmaf(w, f0.x, a0); a1 = fmaf(w, f0.y, a1);
            a2 = fmaf(w, f1.x, a2); a3 = fmaf(w, f1.y, a3);
        }
    }
    a0 += __shfl_xor(a0,  8, 64); a1 += __shfl_xor(a1,  8, 64);
    a2 += __shfl_xor(a2,  8, 64); a3 += __shfl_xor(a3,  8, 64);
    a0 += __shfl_xor(a0, 16, 64); a1 += __shfl_xor(a1, 16, 64);
    a2 += __shfl_xor(a2, 16, 64); a3 += __shfl_xor(a3, 16, 64);
    a0 += __shfl_xor(a0, 32, 64); a1 += __shfl_xor(a1, 32, 64);
    a2 += __shfl_xor(a2, 32, 64); a3 += __shfl_xor(a3, 32, 64);

    if (sub == 0) {
        fvec4 o = { a0 + bq.x, a1 + bq.y, a2 + bq.z, a3 + bq.w };
        __builtin_nontemporal_store(o, (fvec4*)(out + n * 32 + (e4 << 2)));
    }
}

// ---------------------------------------------------------------------------
extern "C" void kernel_launch(void* const* d_in, const int* in_sizes, int n_in,
                              void* d_out, int out_size, void* d_ws, size_t ws_size,
                              hipStream_t stream)
{
    const float* feats = (const float*)d_in[0];
    const int*   esrc  = (const int*)d_in[1];
    const int*   edst  = (const int*)d_in[2];
    const float* ew    = (const float*)d_in[3];
    const float* W1    = (const float*)d_in[4];
    const float* b1    = (const float*)d_in[5];
    const float* W2    = (const float*)d_in[6];
    const float* b2    = (const float*)d_in[7];
    float* out = (float*)d_out;

    char*          ws     = (char*)d_ws;
    int*           offs   = (int*)ws;
    int*           bcnt   = (int*)(ws + OFF_BCNT);
    int*           boffs  = (int*)(ws + OFF_BOFFS);
    int*           gcur   = (int*)(ws + OFF_GCUR);
    int*           csrp   = (int*)(ws + OFF_CSR);
    int2*          binned = (int2*)(ws + OFF_YQ);  // aliases Yq; dead before gemm1
    unsigned char* Yq     = (unsigned char*)(ws + OFF_YQ);
    __half*        hw     = (__half*)(ws + OFF_HW);

    (void)hipMemsetAsync(bcnt, 0, NB * sizeof(int), stream);

    k_bucketcnt <<<NTILES,    256, 0, stream>>>(edst, bcnt);
    k_bucketscan<<<1,         512, 0, stream>>>(bcnt, boffs, gcur);
    k_binscatter<<<NTILES,    256, 0, stream>>>(edst, esrc, ew, gcur, binned);
    k_bucketsort<<<NB,        256, 0, stream>>>(binned, boffs, offs, csrp);
    k_gemm1     <<<G1_BLOCKS, 256, 0, stream>>>(feats, W1, Yq);
    k_l1        <<<NN / 4,    256, 0, stream>>>(offs, csrp, Yq, b1, W2, hw);
    k_l2        <<<NN / 4,    256, 0, stream>>>(offs, csrp, hw, b2, out);
}

// Round 15
// 227.992 us; speedup vs baseline: 1.1694x; 1.0132x over previous
//
#include <hip/hip_runtime.h>
#include <hip/hip_fp16.h>

#define NN 100000
#define NE 1600000
#define NEG_SLOPE 0.01f

#define NTL(x) __builtin_nontemporal_load(&(x))
typedef float fvec4 __attribute__((ext_vector_type(4)));
typedef float fvec2 __attribute__((ext_vector_type(2)));

// Coarse buckets: 256 consecutive dst nodes each.
#define NB     391        // ceil(NN/256)
#define TILE   4096       // edges per binning workgroup
#define NTILES 391        // ceil(NE/TILE)
#define CAP    8192       // LDS stage capacity per bucket

// gemm1: 2048 blocks x 4 waves = 8192 waves, ~12 rows each; launch_bounds
// (256,1) so w[64] REALLY lives in VGPRs (round-14: default bounds capped
// VGPR at 44 -> compiler re-loaded W1 per row -> 80 us).
#define G1_BLOCKS 2048
#define G1_WAVES  (G1_BLOCKS * 4)

// ---------------------------------------------------------------------------
// Workspace layout (bytes) — total 26,008,384 B (< 26.4 MB proven).
//   offs  : (NN+1) int  @ 0          (400,004)
//   bcnt  : NB int      @ 400,384
//   boffs : (NB+1) int  @ 402,432
//   gcur  : NB int      @ 404,432
//   csrp  : NE int      @ 408,384    packed (src<<15 | w*32767), by dst, 6.4 MB
//   binned: NE int2     @ 6,808,384  bucket-grouped, 12.8 MB
//   Yq    : NN*64 fp8   @ 6,808,384  (ALIASES binned; binned dead before gemm1)
//   hw    : NN*32 fp16  @ 19,608,384 (6.4 MB)
#define OFF_BCNT  400384
#define OFF_BOFFS 402432
#define OFF_GCUR  404432
#define OFF_CSR   408384
#define OFF_YQ    6808384
#define OFF_HW    19608384

// ---------------------------------------------------------------------------
// A1: per-bucket edge counts (proven round 10).
__global__ __launch_bounds__(256) void k_bucketcnt(const int* __restrict__ dst,
                                                   int* __restrict__ bcnt)
{
    __shared__ int h[NB];
    int t = threadIdx.x;
    for (int i = t; i < NB; i += 256) h[i] = 0;
    __syncthreads();
    int base = blockIdx.x * TILE;
    for (int i = t; i < TILE; i += 256) {
        int e = base + i;
        if (e < NE) atomicAdd(&h[NTL(dst[e]) >> 8], 1);
    }
    __syncthreads();
    for (int i = t; i < NB; i += 256)
        if (h[i]) atomicAdd(&bcnt[i], h[i]);
}

// A2: exclusive scan of bucket counts (proven round 10).
__global__ __launch_bounds__(512) void k_bucketscan(const int* __restrict__ bcnt,
                                                    int* __restrict__ boffs,
                                                    int* __restrict__ gcur)
{
    __shared__ int lds[512];
    int t = threadIdx.x;
    int v = (t < NB) ? bcnt[t] : 0;
    lds[t] = v;
    __syncthreads();
    for (int off = 1; off < 512; off <<= 1) {
        int x = (t >= off) ? lds[t - off] : 0;
        __syncthreads();
        lds[t] += x;
        __syncthreads();
    }
    int excl = lds[t] - v;
    if (t < NB) { boffs[t] = excl; gcur[t] = excl; }
    if (t == NB - 1) boffs[NB] = lds[t];           // == NE
}

// A3: bin edges into bucket-grouped 'binned' (proven round 10).
__global__ __launch_bounds__(256) void k_binscatter(const int* __restrict__ dst,
                                                    const int* __restrict__ esrc,
                                                    const float* __restrict__ ew,
                                                    int* __restrict__ gcur,
                                                    int2* __restrict__ binned)
{
    __shared__ int   hist[NB];
    __shared__ int   cstart[NB];
    __shared__ int   ccur[NB];
    __shared__ int   gb[NB];
    __shared__ int   lds2[256];
    __shared__ int   sdst[TILE];
    __shared__ short sbuck[TILE];
    __shared__ int2  stage[TILE];

    int t = threadIdx.x;
    int base = blockIdx.x * TILE;
    int nvalid = NE - base; if (nvalid > TILE) nvalid = TILE;

    for (int i = t; i < NB; i += 256) hist[i] = 0;
    __syncthreads();
    for (int i = t; i < TILE; i += 256) {
        int e = base + i;
        int d = (e < NE) ? NTL(dst[e]) : -1;
        sdst[i] = d;
        if (d >= 0) atomicAdd(&hist[d >> 8], 1);
    }
    __syncthreads();

    int h0 = (2 * t     < NB) ? hist[2 * t]     : 0;
    int h1 = (2 * t + 1 < NB) ? hist[2 * t + 1] : 0;
    int ps = h0 + h1;
    lds2[t] = ps;
    __syncthreads();
    for (int off = 1; off < 256; off <<= 1) {
        int x = (t >= off) ? lds2[t - off] : 0;
        __syncthreads();
        lds2[t] += x;
        __syncthreads();
    }
    int excl = lds2[t] - ps;
    if (2 * t     < NB) { cstart[2 * t]     = excl;      ccur[2 * t]     = excl; }
    if (2 * t + 1 < NB) { cstart[2 * t + 1] = excl + h0; ccur[2 * t + 1] = excl + h0; }
    __syncthreads();

    for (int i = t; i < TILE; i += 256) {
        int d = sdst[i];
        if (d >= 0) {
            int e = base + i;
            int b = d >> 8;
            int pos = atomicAdd(&ccur[b], 1);
            stage[pos] = make_int2((NTL(esrc[e]) << 8) | (d & 255),
                                   __float_as_int(NTL(ew[e])));
            sbuck[pos] = (short)b;
        }
    }
    __syncthreads();

    for (int i = t; i < NB; i += 256)
        if (hist[i]) gb[i] = atomicAdd(&gcur[i], hist[i]);
    __syncthreads();
    for (int i = t; i < nvalid; i += 256) {
        int b = sbuck[i];
        binned[gb[b] + (i - cstart[b])] = stage[i];
    }
}

// B: per-bucket LDS counting sort -> csrp + offs (proven round 10).
__global__ __launch_bounds__(256) void k_bucketsort(const int2* __restrict__ binned,
                                                    const int* __restrict__ boffs,
                                                    int* __restrict__ offs,
                                                    int* __restrict__ csrp)
{
    __shared__ int nhist[256];
    __shared__ int nstart[256];
    __shared__ int ncur[256];
    __shared__ int lds[256];
    __shared__ int stage[CAP];

    int t = threadIdx.x, b = blockIdx.x;           // grid = NB
    int s0 = boffs[b], s1 = boffs[b + 1];
    int cnt = s1 - s0;

    nhist[t] = 0;
    __syncthreads();
    for (int i = t; i < cnt; i += 256)
        atomicAdd(&nhist[binned[s0 + i].x & 255], 1);
    __syncthreads();

    int v = nhist[t];
    lds[t] = v;
    __syncthreads();
    for (int off = 1; off < 256; off <<= 1) {
        int x = (t >= off) ? lds[t - off] : 0;
        __syncthreads();
        lds[t] += x;
        __syncthreads();
    }
    int excl = lds[t] - v;
    nstart[t] = excl;
    ncur[t] = excl;
    int node = b * 256 + t;
    if (node < NN) offs[node] = s0 + excl;
    if (b == NB - 1 && t == 0) offs[NN] = s1;      // == NE
    __syncthreads();

    for (int i = t; i < cnt; i += 256) {
        int2 r = binned[s0 + i];
        int dl = r.x & 255;
        unsigned src = ((unsigned)r.x) >> 8;
        float w = __int_as_float(r.y);
        unsigned wq = (unsigned)(w * 32767.0f + 0.5f);
        int pos = atomicAdd(&ncur[dl], 1);
        stage[pos] = (int)((src << 15) | wq);
    }
    __syncthreads();
    for (int i = t; i < cnt; i += 256)
        csrp[s0 + i] = stage[i];
}

// ---------------------------------------------------------------------------
// Y = feats @ W1 -> fp8 e4m3. W1 column in 64 VGPRs; launch_bounds(256,1)
// lifts the default VGPR cap so the array is truly register-resident.
__global__ __launch_bounds__(256, 1) void k_gemm1(const float* __restrict__ feats,
                                                  const float* __restrict__ W1,
                                                  unsigned char* __restrict__ Yq)
{
    int lane = threadIdx.x & 63;
    int wid = (blockIdx.x * 256 + threadIdx.x) >> 6;

    float w[64];
    #pragma unroll
    for (int k = 0; k < 64; ++k) w[k] = W1[k * 64 + lane];

    for (int r = wid; r < NN; r += G1_WAVES) {
        const float4* fr = (const float4*)(feats + r * 64);
        float acc = 0.f;
        #pragma unroll
        for (int i = 0; i < 16; ++i) {
            float4 v = fr[i];
            acc = fmaf(v.x, w[4 * i + 0], acc);
            acc = fmaf(v.y, w[4 * i + 1], acc);
            acc = fmaf(v.z, w[4 * i + 2], acc);
            acc = fmaf(v.w, w[4 * i + 3], acc);
        }
        float accN = __shfl_xor(acc, 1, 64);
        int v01 = __builtin_amdgcn_cvt_pk_fp8_f32(acc, accN, 0, false);
        int v23 = __shfl_xor(v01, 2, 64);
        int word = (v01 & 0xFFFF) | (v23 << 16);
        if ((lane & 3) == 0)
            ((int*)(Yq + r * 64))[lane >> 2] = word;
    }
}

#define WDEC(c) ((float)((c) & 0x7fffu) * (1.0f / 32767.0f))

// ---------------------------------------------------------------------------
// Layer 1 (proven round 14): 4 edge-slots x 16 lanes x 4B fp8 gather; 8-shfl
// reduction; W2 in 32 VGPRs; h staged via 1 KB per-wave LDS.
__global__ __launch_bounds__(256) void k_l1(const int* __restrict__ offs,
                                            const int* __restrict__ csrp,
                                            const unsigned char* __restrict__ Yq,
                                            const float* __restrict__ b1,
                                            const float* __restrict__ W2,
                                            __half* __restrict__ hw)
{
    __shared__ __align__(16) float sh[4][64];      // per-wave h staging
    int tid = threadIdx.x;
    int lane = tid & 63;
    int wv = tid >> 6;
    int n = blockIdx.x * 4 + wv;                   // grid exact = NN waves
    int half = lane >> 5, c = lane & 31;

    float w2r[32];
    #pragma unroll
    for (int kk = 0; kk < 32; ++kk)
        w2r[kk] = W2[(half * 32 + kk) * 32 + c];

    int sub = lane >> 4;          // edge slot 0..3
    int e4  = lane & 15;          // col quad: cols [4*e4, 4*e4+4)
    const float4 bq = *(const float4*)(b1 + (e4 << 2));

    int start = offs[n], end = offs[n + 1];
    float a0 = 0.f, a1 = 0.f, a2 = 0.f, a3 = 0.f;
    for (int base = start; base < end; base += 64) {
        int m = end - base; if (m > 64) m = 64;
        int ed = (lane < m) ? NTL(csrp[base + lane]) : 0;   // pad: s=0, w=0
        int iters = (m + 3) >> 2;
        for (int i = 0; i < iters; ++i) {
            unsigned cc = (unsigned)__shfl(ed, (i << 2) + sub, 64);
            unsigned w8 = *(const unsigned*)(Yq + (cc >> 15) * 64 + (e4 << 2));
            float w = WDEC(cc);
            fvec2 lo = __builtin_amdgcn_cvt_pk_f32_fp8((int)w8, false);
            fvec2 hi = __builtin_amdgcn_cvt_pk_f32_fp8((int)w8, true);
            a0 = fmaf(w, lo.x, a0); a1 = fmaf(w, lo.y, a1);
            a2 = fmaf(w, hi.x, a2); a3 = fmaf(w, hi.y, a3);
        }
    }
    a0 += __shfl_xor(a0, 16, 64); a1 += __shfl_xor(a1, 16, 64);
    a2 += __shfl_xor(a2, 16, 64); a3 += __shfl_xor(a3, 16, 64);
    a0 += __shfl_xor(a0, 32, 64); a1 += __shfl_xor(a1, 32, 64);
    a2 += __shfl_xor(a2, 32, 64); a3 += __shfl_xor(a3, 32, 64);

    float h0 = a0 + bq.x, h1 = a1 + bq.y, h2 = a2 + bq.z, h3 = a3 + bq.w;
    h0 = h0 >= 0.f ? h0 : NEG_SLOPE * h0;  h1 = h1 >= 0.f ? h1 : NEG_SLOPE * h1;
    h2 = h2 >= 0.f ? h2 : NEG_SLOPE * h2;  h3 = h3 >= 0.f ? h3 : NEG_SLOPE * h3;

    if (sub == 0)
        *(float4*)&sh[wv][e4 << 2] = make_float4(h0, h1, h2, h3);
    __builtin_amdgcn_wave_barrier();               // keep write before reads

    float p = 0.f;
    #pragma unroll
    for (int q = 0; q < 8; ++q) {                  // broadcast reads, no conflicts
        float4 hv = *(const float4*)&sh[wv][(half << 5) + (q << 2)];
        p = fmaf(hv.x, w2r[4 * q + 0], p);
        p = fmaf(hv.y, w2r[4 * q + 1], p);
        p = fmaf(hv.z, w2r[4 * q + 2], p);
        p = fmaf(hv.w, w2r[4 * q + 3], p);
    }
    p += __shfl_xor(p, 32, 64);
    if (lane < 32) hw[n * 32 + lane] = __float2half(p);
}

// ---------------------------------------------------------------------------
// Layer 2 (proven round 14): 8 edge-slots x 8 lanes x 8B fp16; 12-shfl RED.
__global__ __launch_bounds__(256) void k_l2(const int* __restrict__ offs,
                                            const int* __restrict__ csrp,
                                            const __half* __restrict__ hw,
                                            const float* __restrict__ b2,
                                            float* __restrict__ out)
{
    int tid = threadIdx.x;
    int lane = tid & 63;
    int n = blockIdx.x * 4 + (tid >> 6);           // grid exact = NN waves
    int sub = lane >> 3;          // edge slot 0..7
    int e4  = lane & 7;           // col quad: cols [4*e4, 4*e4+4)
    const float4 bq = *(const float4*)(b2 + (e4 << 2));

    int start = offs[n], end = offs[n + 1];
    float a0 = 0.f, a1 = 0.f, a2 = 0.f, a3 = 0.f;
    for (int base = start; base < end; base += 64) {
        int m = end - base; if (m > 64) m = 64;
        int ed = (lane < m) ? NTL(csrp[base + lane]) : 0;   // pad: s=0, w=0
        int iters = (m + 7) >> 3;
        for (int i = 0; i < iters; ++i) {
            unsigned cc = (unsigned)__shfl(ed, (i << 3) + sub, 64);
            int2 raw = *(const int2*)(hw + (cc >> 15) * 32 + (e4 << 2));
            float w = WDEC(cc);
            float2 f0 = __half22float2(((const __half2*)&raw)[0]);
            float2 f1 = __half22float2(((const __half2*)&raw)[1]);
            a0 = fmaf(w, f0.x, a0); a1 = fmaf(w, f0.y, a1);
            a2 = fmaf(w, f1.x, a2); a3 = fmaf(w, f1.y, a3);
        }
    }
    a0 += __shfl_xor(a0,  8, 64); a1 += __shfl_xor(a1,  8, 64);
    a2 += __shfl_xor(a2,  8, 64); a3 += __shfl_xor(a3,  8, 64);
    a0 += __shfl_xor(a0, 16, 64); a1 += __shfl_xor(a1, 16, 64);
    a2 += __shfl_xor(a2, 16, 64); a3 += __shfl_xor(a3, 16, 64);
    a0 += __shfl_xor(a0, 32, 64); a1 += __shfl_xor(a1, 32, 64);
    a2 += __shfl_xor(a2, 32, 64); a3 += __shfl_xor(a3, 32, 64);

    if (sub == 0) {
        fvec4 o = { a0 + bq.x, a1 + bq.y, a2 + bq.z, a3 + bq.w };
        __builtin_nontemporal_store(o, (fvec4*)(out + n * 32 + (e4 << 2)));
    }
}

// ---------------------------------------------------------------------------
extern "C" void kernel_launch(void* const* d_in, const int* in_sizes, int n_in,
                              void* d_out, int out_size, void* d_ws, size_t ws_size,
                              hipStream_t stream)
{
    const float* feats = (const float*)d_in[0];
    const int*   esrc  = (const int*)d_in[1];
    const int*   edst  = (const int*)d_in[2];
    const float* ew    = (const float*)d_in[3];
    const float* W1    = (const float*)d_in[4];
    const float* b1    = (const float*)d_in[5];
    const float* W2    = (const float*)d_in[6];
    const float* b2    = (const float*)d_in[7];
    float* out = (float*)d_out;

    char*          ws     = (char*)d_ws;
    int*           offs   = (int*)ws;
    int*           bcnt   = (int*)(ws + OFF_BCNT);
    int*           boffs  = (int*)(ws + OFF_BOFFS);
    int*           gcur   = (int*)(ws + OFF_GCUR);
    int*           csrp   = (int*)(ws + OFF_CSR);
    int2*          binned = (int2*)(ws + OFF_YQ);  // aliases Yq; dead before gemm1
    unsigned char* Yq     = (unsigned char*)(ws + OFF_YQ);
    __half*        hw     = (__half*)(ws + OFF_HW);

    (void)hipMemsetAsync(bcnt, 0, NB * sizeof(int), stream);

    k_bucketcnt <<<NTILES,    256, 0, stream>>>(edst, bcnt);
    k_bucketscan<<<1,         512, 0, stream>>>(bcnt, boffs, gcur);
    k_binscatter<<<NTILES,    256, 0, stream>>>(edst, esrc, ew, gcur, binned);
    k_bucketsort<<<NB,        256, 0, stream>>>(binned, boffs, offs, csrp);
    k_gemm1     <<<G1_BLOCKS, 256, 0, stream>>>(feats, W1, Yq);
    k_l1        <<<NN / 4,    256, 0, stream>>>(offs, csrp, Yq, b1, W2, hw);
    k_l2        <<<NN / 4,    256, 0, stream>>>(offs, csrp, hw, b2, out);
}